// Round 6
// baseline (229.263 us; speedup 1.0000x reference)
//
#include <hip/hip_runtime.h>
#include <hip/hip_bf16.h>

#define B_SZ   4096

typedef short bf16x8 __attribute__((ext_vector_type(8)));
typedef float f32x4  __attribute__((ext_vector_type(4)));

__device__ __forceinline__ short f2bf(float f) {
    __hip_bfloat16 h = __float2bfloat16(f);
    return *reinterpret_cast<short*>(&h);
}
__device__ __forceinline__ float bf2f(unsigned int u16) {
    unsigned int x = u16 << 16;
    float f;
    __builtin_memcpy(&f, &x, 4);
    return f;
}
__device__ __forceinline__ float fsig(float x) {
    return __builtin_amdgcn_rcpf(1.0f + __expf(-x));
}
__device__ __forceinline__ float ftanhf(float x) {
    return 1.0f - 2.0f * __builtin_amdgcn_rcpf(__expf(2.0f * x) + 1.0f);
}
// XOR swizzle for row-major [32][256] bf16 tile (512 B rows)
__device__ __forceinline__ int swz(int row, int cbyte) {
    return row * 512 + (cbyte ^ ((row & 7) << 4));
}
// 16 fp32 -> 16 bf16, scalar RNE converts (known-good path from rounds 1/3);
// compiler packs the union writes into two 16B LDS stores.
__device__ __forceinline__ void pack16(const float* v, bf16x8* out) {
    union { short s[16]; bf16x8 w[2]; } u;
    #pragma unroll
    for (int i = 0; i < 16; ++i) u.s[i] = f2bf(v[i]);
    out[0] = u.w[0];
    out[1] = u.w[1];
}

// ---------------------------------------------------------------------------
// Kernel 0: weights -> fragment-major bf16 layout wfrag[g][ks][j][kh][8]
__global__ void prep_kernel(const float* __restrict__ wih, const float* __restrict__ whh,
                            short* __restrict__ wfrag) {
    int idx = blockIdx.x * 256 + threadIdx.x;     // 3*8*128*4*8 = 98304
    int i   = idx & 7;
    int kh  = (idx >> 3) & 3;
    int j   = (idx >> 5) & 127;
    int gks = idx >> 12;                          // g*8+ks
    int g   = gks >> 3, ks = gks & 7;
    int k   = ks * 32 + kh * 8 + i;
    int r   = g * 128 + j;
    float v = (k < 128) ? wih[r * 128 + k] : whh[r * 128 + (k - 128)];
    wfrag[idx] = f2bf(v);
}

// ---------------------------------------------------------------------------
// Kernel 1: fused feature-build + merged GRU GEMM (K=256) + masked mean.
// Block = ONE node = 32 rows, 8 waves (512 thr). Wave w owns gate columns
// [16w,16w+16). 32 acc regs/lane -> 6 waves/SIMD -> 3 blocks/CU.
// Staging: every wave converts 16 floats (packed RNE) -> 2 LDS writes.
//   w0: e_emb cols 0-31 (+mask), w1: e_emb 32-63, w2: ts 0-31, w3: ts 32-63,
//   w4-7: hidden cols (wv-4)*32 .. +32.   (h = lane>>5 picks 16-col half)
__global__ __launch_bounds__(512, 6) void gru_agg_kernel(
    const int*   __restrict__ ngh_id,
    const int*   __restrict__ e_idx,
    const float* __restrict__ ngh_ts,
    const float* __restrict__ hidden_store,
    const float* __restrict__ e_feat,
    const float* __restrict__ basis_freq,
    const float* __restrict__ phase,
    const float* __restrict__ cut_time,
    const short* __restrict__ wfrag,
    const float* __restrict__ b_ih,
    const float* __restrict__ b_hh,
    float*       __restrict__ agg)
{
    __shared__ __align__(16) char sT[32 * 512];   // [32 rows][256 bf16 cols] swizzled
    __shared__ float sMask[32];
    __shared__ float sInv;

    const int bid  = blockIdx.x;                  // node index 0..12287
    const int tid  = threadIdx.x;
    const int lane = tid & 63;
    const int wv   = tid >> 6;

    // ---- wave-specialized staging: 16 floats per lane ----
    {
        const int row  = lane & 31;
        const int h    = lane >> 5;               // 16-col half
        const int flat = bid * 32 + row;
        float v[16];
        int cb;                                   // tile byte offset of first col

        if (wv < 2) {                             // e_emb
            if (wv == 0) {                        // + mask/count
                const int nid = ngh_id[flat];
                unsigned long long mb = __ballot(nid != 0);
                if (lane < 32) sMask[row] = (nid != 0) ? 1.0f : 0.0f;
                if (lane == 0) {
                    int c = __popcll(mb & 0xFFFFFFFFull);
                    sInv = 1.0f / (float)(c > 1 ? c : 1);
                }
            }
            const int c0 = wv * 32 + h * 16;
            const int e  = e_idx[flat];
            const float4* src = reinterpret_cast<const float4*>(e_feat + (size_t)e * 64 + c0);
            #pragma unroll
            for (int t = 0; t < 4; ++t) *reinterpret_cast<float4*>(&v[t * 4]) = src[t];
            cb = c0 * 2;
        } else if (wv < 4) {                      // ts_emb
            const float dt = cut_time[bid & (B_SZ - 1)] - ngh_ts[flat];
            const int f0 = (wv - 2) * 32 + h * 16;
            #pragma unroll
            for (int i = 0; i < 16; ++i)
                v[i] = __cosf(dt * basis_freq[f0 + i] + phase[f0 + i]);
            cb = 128 + f0 * 2;
        } else {                                  // hidden
            const int c0 = (wv - 4) * 32 + h * 16;
            const float4* src = reinterpret_cast<const float4*>(hidden_store + (size_t)flat * 128 + c0);
            #pragma unroll
            for (int t = 0; t < 4; ++t) *reinterpret_cast<float4*>(&v[t * 4]) = src[t];
            cb = 256 + c0 * 2;
        }
        bf16x8 w[2];
        pack16(v, w);
        *reinterpret_cast<bf16x8*>(&sT[swz(row, cb)])      = w[0];
        *reinterpret_cast<bf16x8*>(&sT[swz(row, cb + 16)]) = w[1];
    }
    __syncthreads();

    // ---- K-loop: K=256 merged GEMM, M=32 (2 m-frags) ----
    const int l15 = lane & 15;
    const int kh  = lane >> 4;
    const int jc  = (wv << 4) + l15;

    f32x4 ar[2], az[2], axn[2], ahn[2];
    #pragma unroll
    for (int mf = 0; mf < 2; ++mf) {
        ar[mf]  = (f32x4){0.f, 0.f, 0.f, 0.f};
        az[mf]  = (f32x4){0.f, 0.f, 0.f, 0.f};
        axn[mf] = (f32x4){0.f, 0.f, 0.f, 0.f};
        ahn[mf] = (f32x4){0.f, 0.f, 0.f, 0.f};
    }

    #pragma unroll
    for (int ks = 0; ks < 8; ++ks) {
        bf16x8 a[2];
        #pragma unroll
        for (int mf = 0; mf < 2; ++mf)
            a[mf] = *reinterpret_cast<const bf16x8*>(&sT[swz(mf * 16 + l15, ks * 64 + kh * 16)]);
        bf16x8 br = *reinterpret_cast<const bf16x8*>(wfrag + (((((0 * 8 + ks) * 128 + jc) << 2) + kh) << 3));
        bf16x8 bz = *reinterpret_cast<const bf16x8*>(wfrag + (((((1 * 8 + ks) * 128 + jc) << 2) + kh) << 3));
        bf16x8 bn = *reinterpret_cast<const bf16x8*>(wfrag + (((((2 * 8 + ks) * 128 + jc) << 2) + kh) << 3));
        #pragma unroll
        for (int mf = 0; mf < 2; ++mf)
            ar[mf] = __builtin_amdgcn_mfma_f32_16x16x32_bf16(a[mf], br, ar[mf], 0, 0, 0);
        #pragma unroll
        for (int mf = 0; mf < 2; ++mf)
            az[mf] = __builtin_amdgcn_mfma_f32_16x16x32_bf16(a[mf], bz, az[mf], 0, 0, 0);
        if (ks < 4) {
            #pragma unroll
            for (int mf = 0; mf < 2; ++mf)
                axn[mf] = __builtin_amdgcn_mfma_f32_16x16x32_bf16(a[mf], bn, axn[mf], 0, 0, 0);
        } else {
            #pragma unroll
            for (int mf = 0; mf < 2; ++mf)
                ahn[mf] = __builtin_amdgcn_mfma_f32_16x16x32_bf16(a[mf], bn, ahn[mf], 0, 0, 0);
        }
    }

    // ---- epilogue: gates, h_new, masked sum over the node's 32 rows ----
    const float brz = b_ih[jc] + b_hh[jc];
    const float bzz = b_ih[128 + jc] + b_hh[128 + jc];
    const float bin = b_ih[256 + jc];
    const float bhn = b_hh[256 + jc];

    float s = 0.f;
    #pragma unroll
    for (int mf = 0; mf < 2; ++mf) {
        #pragma unroll
        for (int i = 0; i < 4; ++i) {
            const int row = mf * 16 + kh * 4 + i;     // C/D: col=l15, row=kh*4+i
            const float rr = fsig(ar[mf][i] + brz);
            const float zz = fsig(az[mf][i] + bzz);
            const float nn = ftanhf(axn[mf][i] + bin + rr * (ahn[mf][i] + bhn));
            const float hc = bf2f(*reinterpret_cast<const unsigned short*>(&sT[swz(row, 256 + jc * 2)]));
            s += ((1.0f - zz) * nn + zz * hc) * sMask[row];
        }
    }
    s += __shfl_xor(s, 16, 64);
    s += __shfl_xor(s, 32, 64);
    if (lane < 16)
        agg[(size_t)bid * 128 + jc] = s * sInv;
}

// ---------------------------------------------------------------------------
// Kernel 2: emb = relu([node_raw, agg] @ W_out^T + b_out); 16 nodes/block
__global__ __launch_bounds__(256) void emb_kernel(
    const int*   __restrict__ src_ids, const int* __restrict__ tgt_ids,
    const int*   __restrict__ bad_ids, const float* __restrict__ n_feat,
    const float* __restrict__ W_out,   const float* __restrict__ b_out,
    const float* __restrict__ agg,     float* __restrict__ emb)
{
    __shared__ float sv[16][192];
    const int base = blockIdx.x * 16;
    const int j  = threadIdx.x & 63;
    const int ng = threadIdx.x >> 6;
    #pragma unroll
    for (int n0 = 0; n0 < 4; ++n0) {
        const int n = ng * 4 + n0;
        const int node = base + n;
        int id;
        if (node < B_SZ)          id = src_ids[node];
        else if (node < 2 * B_SZ) id = tgt_ids[node - B_SZ];
        else                      id = bad_ids[node - 2 * B_SZ];
        sv[n][j]       = n_feat[(size_t)id * 64 + j];
        sv[n][64 + j]  = agg[(size_t)node * 128 + j];
        sv[n][128 + j] = agg[(size_t)node * 128 + 64 + j];
    }
    __syncthreads();
    float acc[4];
    const float bj = b_out[j];
    #pragma unroll
    for (int n0 = 0; n0 < 4; ++n0) acc[n0] = bj;
    const float4* wr = reinterpret_cast<const float4*>(W_out + j * 192);
    #pragma unroll 4
    for (int c = 0; c < 48; ++c) {
        float4 w = wr[c];
        #pragma unroll
        for (int n0 = 0; n0 < 4; ++n0) {
            const float* s = &sv[ng * 4 + n0][c * 4];
            acc[n0] += w.x * s[0] + w.y * s[1] + w.z * s[2] + w.w * s[3];
        }
    }
    #pragma unroll
    for (int n0 = 0; n0 < 4; ++n0)
        emb[(size_t)(base + ng * 4 + n0) * 64 + j] = fmaxf(acc[n0], 0.0f);
}

// ---------------------------------------------------------------------------
// Kernel 3: merge MLP; 16 pairs/block
__global__ __launch_bounds__(256) void merge_kernel(
    const float* __restrict__ emb,  const float* __restrict__ fc1_w,
    const float* __restrict__ fc1_b, const float* __restrict__ fc2_w,
    const float* __restrict__ fc2_b, float* __restrict__ out)
{
    __shared__ float se[16][192];
    const int base = blockIdx.x * 16;
    const int j  = threadIdx.x & 63;
    const int ng = threadIdx.x >> 6;
    #pragma unroll
    for (int p0 = 0; p0 < 4; ++p0) {
        const int p = ng * 4 + p0;
        const int i = base + p;
        se[p][j]       = emb[(size_t)i * 64 + j];
        se[p][64 + j]  = emb[(size_t)(B_SZ + i) * 64 + j];
        se[p][128 + j] = emb[(size_t)(2 * B_SZ + i) * 64 + j];
    }
    __syncthreads();
    const float4* w1 = reinterpret_cast<const float4*>(fc1_w + j * 128);
    float sp[4] = {0, 0, 0, 0}, tp[4] = {0, 0, 0, 0}, bp[4] = {0, 0, 0, 0};
    #pragma unroll 4
    for (int c = 0; c < 16; ++c) {
        float4 wa = w1[c];
        float4 wb = w1[16 + c];
        #pragma unroll
        for (int p0 = 0; p0 < 4; ++p0) {
            const float* s = se[ng * 4 + p0];
            const float* sa = &s[c * 4];
            sp[p0] += wa.x * sa[0] + wa.y * sa[1] + wa.z * sa[2] + wa.w * sa[3];
            const float* st = &s[64 + c * 4];
            tp[p0] += wb.x * st[0] + wb.y * st[1] + wb.z * st[2] + wb.w * st[3];
            const float* sb = &s[128 + c * 4];
            bp[p0] += wb.x * sb[0] + wb.y * sb[1] + wb.z * sb[2] + wb.w * sb[3];
        }
    }
    const float b1 = fc1_b[j];
    const float w2 = fc2_w[j];
    #pragma unroll
    for (int p0 = 0; p0 < 4; ++p0) {
        float p = fmaxf(b1 + sp[p0] + tp[p0], 0.f) * w2;
        float n = fmaxf(b1 + sp[p0] + bp[p0], 0.f) * w2;
        #pragma unroll
        for (int m = 32; m >= 1; m >>= 1) {
            p += __shfl_xor(p, m, 64);
            n += __shfl_xor(n, m, 64);
        }
        if (j == 0) {
            const int i = base + ng * 4 + p0;
            out[2 * i]     = p + fc2_b[0];
            out[2 * i + 1] = n + fc2_b[0];
        }
    }
}

// ---------------------------------------------------------------------------
extern "C" void kernel_launch(void* const* d_in, const int* in_sizes, int n_in,
                              void* d_out, int out_size, void* d_ws, size_t ws_size,
                              hipStream_t stream) {
    const int*   src_ids  = (const int*)  d_in[0];
    const int*   tgt_ids  = (const int*)  d_in[1];
    const int*   bad_ids  = (const int*)  d_in[2];
    const float* cut_time = (const float*)d_in[3];
    const int*   ngh_id   = (const int*)  d_in[4];
    const int*   e_idx    = (const int*)  d_in[5];
    const float* ngh_ts   = (const float*)d_in[6];
    const float* hidden   = (const float*)d_in[7];
    const float* n_feat   = (const float*)d_in[8];
    const float* e_feat   = (const float*)d_in[9];
    const float* basis    = (const float*)d_in[10];
    const float* phase    = (const float*)d_in[11];
    const float* W_ih     = (const float*)d_in[12];
    const float* W_hh     = (const float*)d_in[13];
    const float* b_ih     = (const float*)d_in[14];
    const float* b_hh     = (const float*)d_in[15];
    const float* W_out    = (const float*)d_in[16];
    const float* b_out    = (const float*)d_in[17];
    const float* fc1_w    = (const float*)d_in[18];
    const float* fc1_b    = (const float*)d_in[19];
    const float* fc2_w    = (const float*)d_in[20];
    const float* fc2_b    = (const float*)d_in[21];

    char* ws = (char*)d_ws;
    short* wfrag = (short*)(ws);                       // 98304*2 = 196608 B
    float* agg   = (float*)(ws + 196608);              // 12288*128*4 = 6291456 B
    float* emb   = (float*)(ws + 196608 + 6291456);    // 12288*64*4  = 3145728 B
    float* out   = (float*)d_out;

    hipLaunchKernelGGL(prep_kernel, dim3(384), dim3(256), 0, stream, W_ih, W_hh, wfrag);
    hipLaunchKernelGGL(gru_agg_kernel, dim3(12288), dim3(512), 0, stream,
                       ngh_id, e_idx, ngh_ts, hidden, e_feat, basis, phase, cut_time,
                       wfrag, b_ih, b_hh, agg);
    hipLaunchKernelGGL(emb_kernel, dim3(768), dim3(256), 0, stream,
                       src_ids, tgt_ids, bad_ids, n_feat, W_out, b_out, agg, emb);
    hipLaunchKernelGGL(merge_kernel, dim3(256), dim3(256), 0, stream,
                       emb, fc1_w, fc1_b, fc2_w, fc2_b, out);
}